// Round 12
// baseline (1166.767 us; speedup 1.0000x reference)
//
#include <hip/hip_runtime.h>

// FFJORD B=4096 D=64 C=16 H=512, NBIJ=2, NSTEPS=8 RK4 -> 64 sequential MLP+VJP evals.
// Round 18 = Round 17 resubmitted verbatim (container infra failure, no kernel verdict).
// R15/R16 fit time ~ 460us + 1.27us*(KB/eval). This round cuts the bf16 leftovers:
// (1) GEMM1 K=96 decomposed: cond-part -> per-bijector cbias[16][512] (one K=32 MFMA),
//     t-part -> te*w1t[n]; per-eval GEMM1 is K=64 i8 over y only (exact per-row scale
//     via wave shfl-max; W1y i8 per-col scales). W1 stream 96 -> 32 KB.
// (2) W3f -> i8 (h2 quantizes at 127 like h1; per-col d scales; dequant folded into
//     the f_s atomicAdd). W3 stream 64 -> 32 KB; h2A LDS 16.6 -> 8.4 KB.
// Stream 416 -> 320 KB/eval (-23%). Epilogue n-constants hoisted per bijector.

typedef __attribute__((ext_vector_type(8))) short short8;
typedef __attribute__((ext_vector_type(4))) float f32x4;
typedef __attribute__((ext_vector_type(4))) int int4v;

#define MFMA_B16(a, b, c) __builtin_amdgcn_mfma_f32_16x16x32_bf16((a), (b), (c), 0, 0, 0)
#define MFMA_I8(a, b, c)  __builtin_amdgcn_mfma_i32_16x16x64_i8((a), (b), (c), 0, 0, 0)

__device__ __forceinline__ unsigned short f2bf(float f) {
  union { float f; unsigned u; } v; v.f = f;
  return (unsigned short)((v.u + 0x7FFFu + ((v.u >> 16) & 1u)) >> 16);
}
__device__ __forceinline__ float bf2f(unsigned short u) {
  union { unsigned u; float f; } v; v.u = ((unsigned)u) << 16; return v.f;
}
__device__ __forceinline__ float fast_tanh(float x) {
  float e = __expf(2.f * x);
  return 1.f - 2.f * __builtin_amdgcn_rcpf(e + 1.f);
}

// ws layout (byte offsets):
// W2f8 i8  [2][8p][512n][64k] @ 0       (swizzled granules: k = p*64 + (kk^((n>>1&3)<<4)))
// W1y8 i8  [2][512n][64k]     @ 524288  (W1 rows 0..63, per-col scale s1[n])
// W3f8 i8  [2][64d][512h]     @ 589824  (W3^T, per-col scale s3[d])
// W3b  bf16 [2][512][64]      @ ush 327680 (plain W3: B for e3)
// W1u  bf16 [2][512][64]      @ ush 393216 (W1u[h][d]=W1[d][h]: B for u)
// W1c  bf16 [2][512][32]      @ ush 458752 (W1 rows 64..79, cols padded 16..31=0)
// w1t  f32 [2][512]           @ f32 245760 (W1 row 80)
// s2   f32 [2][512]           @ f32 246784 (colmax |W2[:,n]|)
// s1   f32 [2][512]           @ f32 247808 (colmax |W1[0:64,n]|)
// s3   f32 [2][64]            @ f32 248832 (colmax |W3[:,d]|)

__global__ void prep_scales(const float* __restrict__ W1, const float* __restrict__ W2,
                            const float* __restrict__ W3, float* __restrict__ wsf) {
  int idx = blockIdx.x * 256 + threadIdx.x;
  if (idx < 1024) {
    int ib = idx >> 9, n = idx & 511;
    const float* W = W2 + (size_t)ib * 262144;
    float m = 0.f;
    for (int k = 0; k < 512; ++k) m = fmaxf(m, fabsf(W[(size_t)k * 512 + n]));
    wsf[246784 + idx] = fmaxf(m, 1e-8f);
  } else if (idx < 2048) {
    int i2 = idx - 1024, ib = i2 >> 9, n = i2 & 511;
    const float* W = W1 + (size_t)ib * 41472;
    float m = 0.f;
    for (int k = 0; k < 64; ++k) m = fmaxf(m, fabsf(W[(size_t)k * 512 + n]));
    wsf[247808 + i2] = fmaxf(m, 1e-8f);
  } else if (idx < 2176) {
    int i2 = idx - 2048, ib = i2 >> 6, d = i2 & 63;
    const float* W = W3 + (size_t)ib * 32768;
    float m = 0.f;
    for (int h = 0; h < 512; ++h) m = fmaxf(m, fabsf(W[(size_t)h * 64 + d]));
    wsf[248832 + i2] = fmaxf(m, 1e-8f);
  }
}

__global__ void prep_pack(const float* __restrict__ W1, const float* __restrict__ W2,
                          const float* __restrict__ W3, unsigned short* __restrict__ ws) {
  int o = blockIdx.x * 256 + threadIdx.x;
  char* ws8 = (char*)ws;
  const float* wsf = (const float*)ws;
  if (o < 524288) {
    int ib = o >> 18, b2 = o & 262143;
    int p = b2 >> 15, r2 = b2 & 32767, n = r2 >> 6, kk = r2 & 63;
    int k = p * 64 + (kk ^ (((n >> 1) & 3) << 4));
    float w = W2[(size_t)ib * 262144 + (size_t)k * 512 + n];
    float s = wsf[246784 + ib * 512 + n];
    int q = (int)rintf(w * (127.f / s));
    q = q > 127 ? 127 : (q < -127 ? -127 : q);
    ws8[o] = (char)q;
  } else if (o < 589824) {
    int o2 = o - 524288;
    int ib = o2 >> 15, r = o2 & 32767, n = r >> 6, k = r & 63;
    float w = W1[(size_t)ib * 41472 + (size_t)k * 512 + n];
    float s = wsf[247808 + ib * 512 + n];
    int q = (int)rintf(w * (127.f / s));
    q = q > 127 ? 127 : (q < -127 ? -127 : q);
    ws8[524288 + o2] = (char)q;
  } else if (o < 655360) {
    int o2 = o - 589824;
    int ib = o2 >> 15, r = o2 & 32767, d = r >> 9, h = r & 511;
    float w = W3[(size_t)ib * 32768 + (size_t)h * 64 + d];
    float s = wsf[248832 + ib * 64 + d];
    int q = (int)rintf(w * (127.f / s));
    q = q > 127 ? 127 : (q < -127 ? -127 : q);
    ws8[589824 + o2] = (char)q;
  } else if (o < 720896) {
    int o2 = o - 655360;                     // plain W3 copy [2][512][64]
    ws[327680 + o2] = f2bf(W3[o2]);
  } else if (o < 786432) {
    int o2 = o - 720896;
    int ib = o2 >> 15, r = o2 & 32767, h = r >> 6, d = r & 63;
    ws[393216 + o2] = f2bf(W1[(size_t)ib * 41472 + (size_t)d * 512 + h]);
  } else if (o < 819200) {
    int o2 = o - 786432;
    int ib = o2 >> 14, r = o2 & 16383, n = r >> 5, c = r & 31;
    ws[458752 + o2] = (c < 16) ? f2bf(W1[(size_t)ib * 41472 + (size_t)(64 + c) * 512 + n])
                               : (unsigned short)0;
  } else if (o < 820224) {
    int o2 = o - 819200;
    int ib = o2 >> 9, n = o2 & 511;
    ((float*)ws)[245760 + o2] = W1[(size_t)ib * 41472 + 80 * 512 + n];
  }
}

#define H8 528    // i8 h1/v/h2 buffer stride, bytes
#define INV2 (1.f / 16129.f)   // 1/(127*127)

// Per-wave async stage of one 2KB slice (own 32 rows x 64 bytes) of a 32KB i8 panel.
#define ISSUE_STAGE(WP, KS, BUF) do {                                                   \
    const char* _s = (WP) + (KS) * 32768 + (wave << 11) + (lane << 4);                  \
    char* _d = &Bst[(BUF)][wave << 11];                                                 \
    __builtin_amdgcn_global_load_lds(                                                   \
        (const __attribute__((address_space(1))) void*)_s,                              \
        (__attribute__((address_space(3))) void*)_d, 16, 0, 0);                         \
    __builtin_amdgcn_global_load_lds(                                                   \
        (const __attribute__((address_space(1))) void*)(_s + 1024),                     \
        (__attribute__((address_space(3))) void*)(_d + 1024), 16, 0, 0);                \
  } while (0)

__global__ __launch_bounds__(1024) void ffjord_mfma(
    const float* __restrict__ x, const float* __restrict__ cond, const float* __restrict__ eps,
    const float* __restrict__ b1g, const float* __restrict__ b2g, const float* __restrict__ b3g,
    const unsigned short* __restrict__ ws, float* __restrict__ out) {
  __shared__ __align__(16) char scratch[2 * 16 * H8];  // h1A8 | vA8; prologue: epsA/condA
  __shared__ __align__(16) char h2A8[16 * H8];         // h2 as i8 (q = round(h2*127))
  __shared__ __align__(16) char zA8[16 * 64];          // y as i8 (exact per-row scale)
  __shared__ float cbias[16][512];                     // cond@W1c + b1 (per bijector)
  __shared__ __align__(16) char Bst[3][32768];         // staging ring: 3 x 32KB panels
  __shared__ float f_s[16][64];
  __shared__ float l_row[16], ld_row[16], ldacc[16];
  __shared__ int sgu[16];                              // per-bijector rowmax |u| bits
  __shared__ float sy_s[16];                           // per-eval rowmax |y|

  const int t = threadIdx.x;
  const int wave = t >> 6;
  const int lane = t & 63;
  const int lane15 = lane & 15;
  const int q8 = (lane >> 4) * 8;        // bf16 frag k-offset (ush)
  const int q16 = (lane >> 4) * 16;      // i8 frag k-offset (bytes)
  const int rowb = q8 >> 1;              // C/D row base
  const int row0 = blockIdx.x * 16;
  const int ws32 = wave * 32;            // N-slice base for N=512 GEMMs
  const int nt3 = wave & 3;              // N-tile for GEMM3f
  const int kb3 = (wave >> 2) * 128;     // K-slice byte base for GEMM3f
  const int tm = t >> 6, td = t & 63;

  const int kk2b = q16 ^ (((lane15 >> 1) & 3) << 4);   // staged-panel read swizzle

  char* h1A8 = scratch;
  char* vA8  = scratch + 16 * H8;

  float ycur, ytmp, yacc = 0.f;
  { float xv = x[(size_t)(row0 + tm) * 64 + td]; ycur = xv; ytmp = xv; }
  if (t < 16) { ld_row[t] = 0.f; l_row[t] = 0.f; }

  const float dt = 0.125f;
  const float w06 = dt / 6.f, w13 = dt / 3.f;
  const char* wsb = (const char*)ws;
  const float* wsf = (const float*)ws;

  for (int ib = 0; ib < 2; ++ib) {
    const char* W2f8 = wsb + ib * 262144;
    const char* W1y8 = wsb + 524288 + ib * 32768;
    const char* W3f8 = wsb + 589824 + ib * 32768;
    const unsigned short* W3b = ws + 327680 + ib * 32768;
    const unsigned short* W1u = ws + 393216 + ib * 32768;
    const unsigned short* W1c = ws + 458752 + ib * 16384;
    const float* w1tg = wsf + 245760 + ib * 512;
    const float* s2g  = wsf + 246784 + ib * 512;
    const float* s1g  = wsf + 247808 + ib * 512;
    const float* s3g  = wsf + 248832 + ib * 64;
    const float* b1b = b1g + ib * 512;
    const float* b2b = b2g + ib * 512;
    const float* b3b = b3g + ib * 64;

    // hoisted per-bijector epilogue constants (n-indexed)
    const int n0 = ws32 + lane15, n1 = n0 + 16;
    const float t1_0 = s1g[n0] * INV2, t1_1 = s1g[n1] * INV2;
    const float w1t0 = w1tg[n0],       w1t1 = w1tg[n1];
    const float b2_0 = b2b[n0],        b2_1 = b2b[n1];
    const float s2_0 = s2g[n0],        s2_1 = s2g[n1];
    const float dq2_0 = s2_0 * INV2,   dq2_1 = s2_1 * INV2;
    const float dq3  = s3g[nt3 * 16 + lane15] * INV2;
    const float fb3  = b3b[td];

    // ---- prologue: stage eps/cond into scratch; e3, u, cbias GEMMs ----
    unsigned short* epsA  = (unsigned short*)scratch;          // [16][72] ush
    unsigned short* condA = (unsigned short*)(scratch + 4096); // [16][32] ush
    epsA[tm * 72 + td] = f2bf(eps[((size_t)ib * 4096 + row0 + tm) * 64 + td]);
    if (t < 512) {
      int m = t >> 5, kk = t & 31;
      condA[m * 32 + kk] = (kk < 16) ? f2bf(cond[(size_t)(row0 + m) * 16 + kk])
                                     : (unsigned short)0;
    }
    if (t < 16) sgu[t] = 0;
    __syncthreads();

    float e3r[8], ur[8];
    {
      f32x4 a0 = {0,0,0,0}, a1 = {0,0,0,0}, u0 = {0,0,0,0}, u1 = {0,0,0,0};
      const unsigned short* ap  = epsA + lane15 * 72 + q8;
      const unsigned short* wp3 = W3b + (size_t)(ws32 + lane15) * 64 + q8;
      const unsigned short* wpu = W1u + (size_t)(ws32 + lane15) * 64 + q8;
      #pragma unroll
      for (int kk = 0; kk < 64; kk += 32) {
        short8 a = *(const short8*)(ap + kk);
        a0 = MFMA_B16(a, *(const short8*)(wp3 + kk),           a0);
        a1 = MFMA_B16(a, *(const short8*)(wp3 + 16 * 64 + kk), a1);
        u0 = MFMA_B16(a, *(const short8*)(wpu + kk),           u0);
        u1 = MFMA_B16(a, *(const short8*)(wpu + 16 * 64 + kk), u1);
      }
      #pragma unroll
      for (int rg = 0; rg < 4; ++rg) {
        e3r[rg] = a0[rg]; e3r[4 + rg] = a1[rg];
        ur[rg] = u0[rg];  ur[4 + rg] = u1[rg];
      }
      #pragma unroll
      for (int rg = 0; rg < 4; ++rg) {
        float mr = fmaxf(fabsf(ur[rg]), fabsf(ur[4 + rg]));
        #pragma unroll
        for (int o = 1; o < 16; o <<= 1) mr = fmaxf(mr, __shfl_xor(mr, o));
        if (lane15 == 0) atomicMax(&sgu[rowb + rg], __float_as_int(mr));
      }
      // cbias = cond @ W1c + b1 (single K=32 bf16 MFMA per tile)
      f32x4 c0 = {0,0,0,0}, c1 = {0,0,0,0};
      short8 ac = *(const short8*)(condA + lane15 * 32 + q8);
      const unsigned short* wpc = W1c + (size_t)(ws32 + lane15) * 32 + q8;
      c0 = MFMA_B16(ac, *(const short8*)wpc,             c0);
      c1 = MFMA_B16(ac, *(const short8*)(wpc + 16 * 32), c1);
      #pragma unroll
      for (int tl = 0; tl < 2; ++tl) {
        int n = tl ? n1 : n0;
        float bb = b1b[n];
        f32x4 cc = tl ? c1 : c0;
        #pragma unroll
        for (int rg = 0; rg < 4; ++rg)
          cbias[rowb + rg][n] = cc[rg] + bb;
      }
    }
    __syncthreads();   // sgu+cbias done; scratch free for h1A8/vA8

    float su_[4], qsv[4];
    #pragma unroll
    for (int rg = 0; rg < 4; ++rg) {
      float sg = fmaxf(__int_as_float(sgu[rowb + rg]), 1e-20f);
      su_[rg] = sg * INV2;
      qsv[rg] = 127.f / sg;
    }

    for (int it = 0; it < 32; ++it) {
      const int s = it & 3;
      const float te = (it >> 2) * dt + ((s == 0) ? 0.f : (s == 3) ? dt : 0.5f * dt);

      // ---- P0: deferred RK4 + logdet; y-quant (exact wave rowmax); zero f_s ----
      if (it > 0) {
        int sp = (it - 1) & 3;
        float fv = f_s[tm][td] + fb3;
        if (sp == 0)      { yacc = ycur + w06 * fv; ytmp = ycur + 0.5f * dt * fv; }
        else if (sp == 1) { yacc += w13 * fv;       ytmp = ycur + 0.5f * dt * fv; }
        else if (sp == 2) { yacc += w13 * fv;       ytmp = ycur + dt * fv; }
        else              { float yn = yacc + w06 * fv; ycur = yn; ytmp = yn; }
      }
      f_s[tm][td] = 0.f;
      {
        float my = fabsf(ytmp);
        #pragma unroll
        for (int o = 1; o < 64; o <<= 1) my = fmaxf(my, __shfl_xor(my, o));
        my = fmaxf(my, 1e-20f);
        if (lane == 0) sy_s[tm] = my;
        zA8[tm * 64 + td] = (char)__float2int_rn(ytmp * (127.f / my));
      }
      if (t < 16) {
        if (it > 0) {
          int sp = (it - 1) & 3;
          float lv = l_row[t];
          if (sp == 0)      ldacc[t] = w06 * lv;
          else if (sp < 3)  ldacc[t] += w13 * lv;
          else              ld_row[t] += ldacc[t] + w06 * lv;
        }
        l_row[t] = 0.f;
      }
      if (it == 0) { ISSUE_STAGE(W2f8, 0, 0); ISSUE_STAGE(W2f8, 1, 1); ISSUE_STAGE(W2f8, 2, 2); }
      __syncthreads();

      // ---- P1: i8 GEMM1 (K=64 over y): h1 = tanh(pre + cbias + te*w1t) ----
      {
        int4v a = *(const int4v*)(zA8 + lane15 * 64 + q16);
        int4v b0v = *(const int4v*)(W1y8 + (size_t)n0 * 64 + q16);
        int4v b1v = *(const int4v*)(W1y8 + (size_t)n1 * 64 + q16);
        int4v z4 = {0, 0, 0, 0};
        int4v ac0 = MFMA_I8(a, b0v, z4);
        int4v ac1 = MFMA_I8(a, b1v, z4);
        #pragma unroll
        for (int tl = 0; tl < 2; ++tl) {
          int n = tl ? n1 : n0;
          float t1 = tl ? t1_1 : t1_0;
          float wt = tl ? w1t1 : w1t0;
          int4v ac = tl ? ac1 : ac0;
          #pragma unroll
          for (int rg = 0; rg < 4; ++rg) {
            int m = rowb + rg;
            float pre = (float)ac[rg] * (sy_s[m] * t1) + cbias[m][n] + te * wt;
            float th = fast_tanh(pre);
            int off = m * H8 + n;
            h1A8[off] = (char)__float2int_rn(th * 127.f);
            float v = (1.f - th * th) * ur[tl * 4 + rg];
            vA8[off] = (char)__float2int_rn(v * qsv[rg]);
          }
        }
      }
      __syncthreads();

      // ---- P2: staged dual i8 GEMM (h2 + w share B-frags); l in epilogue ----
      {
        int4v ha0 = {0,0,0,0}, ha1 = {0,0,0,0}, wa0 = {0,0,0,0}, wa1 = {0,0,0,0};
        const char* aph = h1A8 + lane15 * H8;
        const char* apv = vA8 + lane15 * H8;
        #pragma unroll
        for (int ks = 0; ks < 8; ++ks) {
          if (ks < 6)       asm volatile("s_waitcnt vmcnt(4)" ::: "memory");
          else if (ks == 6) asm volatile("s_waitcnt vmcnt(2)" ::: "memory");
          else              asm volatile("s_waitcnt vmcnt(0)" ::: "memory");
          const char* bq = &Bst[ks % 3][wave << 11];
          int4v ah = *(const int4v*)(aph + ks * 64 + q16);
          int4v av = *(const int4v*)(apv + ks * 64 + q16);
          int4v b0 = *(const int4v*)(bq + lane15 * 64 + kk2b);
          int4v b1 = *(const int4v*)(bq + (16 + lane15) * 64 + kk2b);
          asm volatile("s_waitcnt lgkmcnt(0)" ::: "memory");
          __builtin_amdgcn_sched_barrier(0);
          if (ks + 3 < 8) { ISSUE_STAGE(W2f8, ks + 3, (ks + 3) % 3); }
          ha0 = MFMA_I8(ah, b0, ha0);
          ha1 = MFMA_I8(ah, b1, ha1);
          wa0 = MFMA_I8(av, b0, wa0);
          wa1 = MFMA_I8(av, b1, wa1);
        }
        float p0 = 0.f, p1 = 0.f, p2 = 0.f, p3 = 0.f;
        #pragma unroll
        for (int tl = 0; tl < 2; ++tl) {
          int n = tl ? n1 : n0;
          float bias = tl ? b2_1 : b2_0;
          float dq = tl ? dq2_1 : dq2_0;
          float dqw = tl ? s2_1 : s2_0;
          int4v hac = tl ? ha1 : ha0;
          int4v wac = tl ? wa1 : wa0;
          #pragma unroll
          for (int rg = 0; rg < 4; ++rg) {
            float h = fast_tanh((float)hac[rg] * dq + bias);
            h2A8[(rowb + rg) * H8 + n] = (char)__float2int_rn(h * 127.f);
            float g2 = e3r[tl * 4 + rg] * (1.f - h * h);
            float w = (float)wac[rg] * dqw * su_[rg];
            float pc = g2 * w;
            if (rg == 0) p0 += pc; else if (rg == 1) p1 += pc;
            else if (rg == 2) p2 += pc; else p3 += pc;
          }
        }
        #pragma unroll
        for (int o = 1; o < 16; o <<= 1) {
          p0 += __shfl_xor(p0, o); p1 += __shfl_xor(p1, o);
          p2 += __shfl_xor(p2, o); p3 += __shfl_xor(p3, o);
        }
        if (lane15 == 0) {
          atomicAdd(&l_row[rowb + 0], p0); atomicAdd(&l_row[rowb + 1], p1);
          atomicAdd(&l_row[rowb + 2], p2); atomicAdd(&l_row[rowb + 3], p3);
        }
      }
      __syncthreads();

      // ---- P3: prefetch next-eval panels; i8 GEMM3f: f += h2 @ W3 ----
      if (it < 31) { ISSUE_STAGE(W2f8, 0, 0); ISSUE_STAGE(W2f8, 1, 1); ISSUE_STAGE(W2f8, 2, 2); }
      {
        const char* ap3 = h2A8 + lane15 * H8 + kb3;
        const char* wp3 = W3f8 + (size_t)(nt3 * 16 + lane15) * 512 + kb3;
        int4v z4 = {0, 0, 0, 0};
        int4v c = MFMA_I8(*(const int4v*)(ap3 + q16), *(const int4v*)(wp3 + q16), z4);
        c = MFMA_I8(*(const int4v*)(ap3 + 64 + q16), *(const int4v*)(wp3 + 64 + q16), c);
        #pragma unroll
        for (int rg = 0; rg < 4; ++rg)
          atomicAdd(&f_s[rowb + rg][nt3 * 16 + lane15], (float)c[rg] * dq3);
      }
      __syncthreads();
    }

    // ---- bijector finalize: last RK4 stage (s=3) + logdet stage ----
    {
      float fv = f_s[tm][td] + fb3;
      float yn = yacc + w06 * fv;
      ycur = yn; ytmp = yn;
    }
    if (t < 16) { ld_row[t] += ldacc[t] + w06 * l_row[t]; l_row[t] = 0.f; }
    __syncthreads();
  }

  out[(size_t)(row0 + tm) * 65 + td] = ycur;
  if (t < 16) out[(size_t)(row0 + t) * 65 + 64] = ld_row[t];
}

extern "C" void kernel_launch(void* const* d_in, const int* in_sizes, int n_in,
                              void* d_out, int out_size, void* d_ws, size_t ws_size,
                              hipStream_t stream) {
  (void)in_sizes; (void)n_in; (void)out_size; (void)ws_size;
  const float* x    = (const float*)d_in[0];
  const float* cond = (const float*)d_in[1];
  const float* eps  = (const float*)d_in[2];
  const float* W1   = (const float*)d_in[3];
  const float* b1   = (const float*)d_in[4];
  const float* W2   = (const float*)d_in[5];
  const float* b2   = (const float*)d_in[6];
  const float* W3   = (const float*)d_in[7];
  const float* b3   = (const float*)d_in[8];
  float* out = (float*)d_out;
  unsigned short* ws = (unsigned short*)d_ws;

  prep_scales<<<9, 256, 0, stream>>>(W1, W2, W3, (float*)ws);
  const int prep_total = 820224;
  prep_pack<<<(prep_total + 255) / 256, 256, 0, stream>>>(W1, W2, W3, ws);
  ffjord_mfma<<<256, 1024, 0, stream>>>(x, cond, eps, b1, b2, b3, ws, out);
}